// Round 8
// baseline (263.462 us; speedup 1.0000x reference)
//
#include <hip/hip_runtime.h>
#include <math.h>

#define DIMK 2048
#define NSEQ 4096
#define NT (DIMK / 64)  // 32 K-tiles of BK=64
#define EPS 264          // epilogue LDS row stride (u16) — bank-spread

typedef short bf16x8 __attribute__((ext_vector_type(8)));
typedef float f32x16 __attribute__((ext_vector_type(16)));
typedef unsigned short u16;
typedef unsigned short u16x8 __attribute__((ext_vector_type(8)));

__device__ __forceinline__ u16 f32_to_bf16(float f) {
  unsigned u = __float_as_uint(f);
  u += 0x7fffu + ((u >> 16) & 1u);  // round-to-nearest-even
  return (u16)(u >> 16);
}

__device__ __forceinline__ void async16(const u16* g, u16* l) {
  __builtin_amdgcn_global_load_lds(
      (const __attribute__((address_space(1))) unsigned int*)g,
      (__attribute__((address_space(3))) unsigned int*)l,
      16, 0, 0);
}

// -------- fused fp32 -> bf16 cast for x, Wq, Wk (one launch, 16B stores) ----
__global__ __launch_bounds__(256) void cast3_f32_bf16(
    const float* __restrict__ x, const float* __restrict__ wq,
    const float* __restrict__ wk, u16* __restrict__ xb,
    u16* __restrict__ wqb, u16* __restrict__ wkb) {
  const int xN8 = NSEQ * DIMK / 8;
  const int wN8 = DIMK * DIMK / 8;
  int i = blockIdx.x * 256 + threadIdx.x;
  const float* src;
  u16* dst;
  int j;
  if (i < xN8) { src = x; dst = xb; j = i; }
  else if (i < xN8 + wN8) { src = wq; dst = wqb; j = i - xN8; }
  else { src = wk; dst = wkb; j = i - xN8 - wN8; }
  float4 v0 = ((const float4*)src)[j * 2];
  float4 v1 = ((const float4*)src)[j * 2 + 1];
  u16x8 o;
  o[0] = f32_to_bf16(v0.x); o[1] = f32_to_bf16(v0.y);
  o[2] = f32_to_bf16(v0.z); o[3] = f32_to_bf16(v0.w);
  o[4] = f32_to_bf16(v1.x); o[5] = f32_to_bf16(v1.y);
  o[6] = f32_to_bf16(v1.z); o[7] = f32_to_bf16(v1.w);
  ((u16x8*)dst)[j] = o;
}

// ========== 256x256 woven 4-phase NT GEMM mainloop, 32x32x16 MFMA ==========
// Round-7 verified schedule (43% MfmaUtil): barriers, staging, vmcnt ledger,
// LDS image + chunk-XOR swizzle all UNCHANGED. Round-8 parameter change:
// 16x16x32 -> 32x32x16 MFMA (higher pipe ceiling 2382 vs 2075 TF, half the
// instruction count: 32x8cyc vs 64x5cyc per K-tile).
// Per wave 128x64 out = 4x2 tiles of 32x32 -> acc[4][2] f32x16.
// Fragment groups map 1:1 onto round-7's (same read counts, same phases):
//   aLow (rt 0-1, 8 rds) <-> a1 ; aHigh (rt 2-3, 8 rds) <-> a2
//   b0   (ct 0,   4 rds) <-> b01; b1    (ct 1,   4 rds) <-> b23
// so the round-7 liveness ledger transfers verbatim:
//   P1: {CLa(aLow x b0) | rd b1 | CLb} BAR
//   P2: stage A-bot(t+1)->nxt; {CLa(aLow x b1) | rd aHigh | CLb} BAR
//   P3: {CLa(aHigh x b0) CLb} BAR
//   P4: stage B(t+2),A-top(t+2)->cur; vmcnt(6); {CLa(aHigh x b1) |
//       rd aLow',b0'(nxt) | CLb} BAR
// Layouts (32x32x16): A row=lane&31, k=8*(lane>>5)+e (verified-analogy to
// our working 16x16x32 reads: 8 contiguous k per lane); C/D col=lane&31,
// row=(reg&3)+8*(reg>>2)+4*(lane>>5) [m74/m101 verified].
// LDS read addr: row_local*64 + physchunk*8, physchunk=(2ks+lhi)^(lane&7)
// — matches the staged image's phys=logical^(row&7); bank pattern = 8
// lanes per 16B slot at distinct 128B rows, identical structure to the
// round-7 reads that measured 0 conflicts.

#define VM6 asm volatile("s_waitcnt vmcnt(6)" ::: "memory")
#define VM0 asm volatile("s_waitcnt vmcnt(0)" ::: "memory")
#define BAR __builtin_amdgcn_s_barrier()
#define PRIO1 __builtin_amdgcn_s_setprio(1)
#define PRIO0 __builtin_amdgcn_s_setprio(0)
#define NOOP ((void)0)

#define ISSUE(g, t_, reg)                                     \
  do {                                                        \
    const u16* _gp = (g) + (size_t)(t_) * 64 + stg_goff;      \
    async16(_gp, (reg) + tid * 8);                            \
    async16(_gp + (size_t)64 * DIMK, (reg) + 4096 + tid * 8); \
  } while (0)

// ---- fragment read helpers (fragments live at mainloop scope) ----
#define RD_ALOW(bi)                                                       \
  _Pragma("unroll") for (int rt = 0; rt < 2; ++rt)                        \
    _Pragma("unroll") for (int ks = 0; ks < 4; ++ks)                      \
      aLow[rt][ks] =                                                      \
          *(const bf16x8*)&rdA[bi][rt * 2048 + rowOff + ck[ks]];
#define RD_AHIGH(bi)                                                      \
  _Pragma("unroll") for (int rt = 0; rt < 2; ++rt)                        \
    _Pragma("unroll") for (int ks = 0; ks < 4; ++ks)                      \
      aHigh[rt][ks] =                                                     \
          *(const bf16x8*)&rdA[bi][(rt + 2) * 2048 + rowOff + ck[ks]];
#define RD_B0(bi)                                                         \
  _Pragma("unroll") for (int ks = 0; ks < 4; ++ks)                        \
      b0[ks] = *(const bf16x8*)&rdB[bi][rowOff + ck[ks]];
#define RD_B1(bi)                                                         \
  _Pragma("unroll") for (int ks = 0; ks < 4; ++ks)                        \
      b1[ks] = *(const bf16x8*)&rdB[bi][2048 + rowOff + ck[ks]];

// Half-cluster: 4 MFMAs (2 acc-tiles x 2 k-segs); same-acc spacing = 2.
#define CLa(i0, Aa, ct, Bv)                                               \
  _Pragma("unroll") for (int ks = 0; ks < 2; ++ks)                        \
    _Pragma("unroll") for (int i = 0; i < 2; ++i)                         \
      acc[(i0) + i][ct] = __builtin_amdgcn_mfma_f32_32x32x16_bf16(        \
          Aa[i][ks], Bv[ks], acc[(i0) + i][ct], 0, 0, 0);
#define CLb(i0, Aa, ct, Bv)                                               \
  _Pragma("unroll") for (int ks = 2; ks < 4; ++ks)                        \
    _Pragma("unroll") for (int i = 0; i < 2; ++i)                         \
      acc[(i0) + i][ct] = __builtin_amdgcn_mfma_f32_32x32x16_bf16(        \
          Aa[i][ks], Bv[ks], acc[(i0) + i][ct], 0, 0, 0);

#define TILE(bi, SP1, SP3A, SP3B, SP4, VMW)  \
  do {                                       \
    /* P1: aLow x b0, weave b1 reads */      \
    PRIO1;                                   \
    CLa(0, aLow, 0, b0)                      \
    RD_B1(bi);                               \
    CLb(0, aLow, 0, b0)                      \
    PRIO0;                                   \
    BAR;                                     \
    /* P2: aLow x b1, weave aHigh reads */   \
    SP1;                                     \
    PRIO1;                                   \
    CLa(0, aLow, 1, b1)                      \
    RD_AHIGH(bi);                            \
    CLb(0, aLow, 1, b1)                      \
    PRIO0;                                   \
    BAR;                                     \
    /* P3: aHigh x b0 */                     \
    PRIO1;                                   \
    CLa(2, aHigh, 0, b0)                     \
    CLb(2, aHigh, 0, b0)                     \
    PRIO0;                                   \
    BAR;                                     \
    /* P4: stages + counted vmcnt, aHigh x b1, weave next-buf reads */ \
    SP3A;                                    \
    SP3B;                                    \
    SP4;                                     \
    VMW;                                     \
    PRIO1;                                   \
    CLa(2, aHigh, 1, b1)                     \
    RD_ALOW((bi) ^ 1);                       \
    RD_B0((bi) ^ 1);                         \
    CLb(2, aHigh, 1, b1)                     \
    PRIO0;                                   \
    BAR;                                     \
  } while (0)

// Last K-tile: pure dataflow, no stages, no barriers needed.
#define TILE_LAST(bi)           \
  do {                          \
    PRIO1;                      \
    CLa(0, aLow, 0, b0)         \
    RD_B1(bi);                  \
    CLb(0, aLow, 0, b0)         \
    CLa(0, aLow, 1, b1)         \
    RD_AHIGH(bi);               \
    CLb(0, aLow, 1, b1)         \
    CLa(2, aHigh, 0, b0)        \
    CLb(2, aHigh, 0, b0)        \
    CLa(2, aHigh, 1, b1)        \
    CLb(2, aHigh, 1, b1)        \
    PRIO0;                      \
  } while (0)

__device__ __forceinline__ void mainloop256(
    const u16* __restrict__ A, const u16* __restrict__ B, int rowBase,
    int colBase, u16 (*lds)[2][2][8192], f32x16 acc[4][2]) {
  const int tid = threadIdx.x;
  const int lane = tid & 63;
  const int wid = tid >> 6;
  const int wmg = wid >> 2;  // 0,1 : which 128-row half of A-tile
  const int wng = wid & 3;   // 0..3: which 64-row strip of B-tile
  const int lhi = lane >> 5;

  // staging: thread covers row (tid>>3), phys chunk (tid&7); pre-swizzled
  // global source chunk = (tid&7) ^ (row&7)  (linear LDS dest, swizzled src).
  const int stg_goff =
      (tid >> 3) * DIMK + (((tid & 7) ^ ((tid >> 3) & 7)) * 8);
  // frag-read: row_local = (lane&31) within 32-row tile; phys chunk for
  // k-seg ks: (2ks+lhi)^(lane&7), as element offsets:
  const int rowOff = (lane & 31) * 64;
  int ck[4];
#pragma unroll
  for (int ks = 0; ks < 4; ++ks) ck[ks] = ((ks * 2 + lhi) ^ (lane & 7)) * 8;

  const u16* gA0 = A + (size_t)rowBase * DIMK;
  const u16* gA1 = gA0 + (size_t)128 * DIMK;
  const u16* gB0 = B + (size_t)colBase * DIMK;
  const u16* gB1 = gB0 + (size_t)128 * DIMK;

  u16* sA0[2] = {&lds[0][0][0][0], &lds[1][0][0][0]};
  u16* sA1[2] = {&lds[0][0][1][0], &lds[1][0][1][0]};
  u16* sB0[2] = {&lds[0][1][0][0], &lds[1][1][0][0]};
  u16* sB1[2] = {&lds[0][1][1][0], &lds[1][1][1][0]};

  const u16* rdA[2] = {&lds[0][0][wmg][0], &lds[1][0][wmg][0]};
  const u16* rdB[2] = {&lds[0][1][wng >> 1][(wng & 1) * 4096],
                       &lds[1][1][wng >> 1][(wng & 1) * 4096]};

  // fragments live across phases/tiles (read-ahead passes them forward)
  bf16x8 aLow[2][4], aHigh[2][4], b0[4], b1[4];

  // ---- prologue: tile0 fully (8 ops) + B(1)+A-top(1) (6 ops) ----
  ISSUE(gB0, 0, sB0[0]);
  ISSUE(gB1, 0, sB1[0]);
  ISSUE(gA0, 0, sA0[0]);
  ISSUE(gA1, 0, sA1[0]);
  ISSUE(gB0, 1, sB0[1]);
  ISSUE(gB1, 1, sB1[1]);
  ISSUE(gA0, 1, sA0[1]);
  VM6;  // retire tile0's 8; leave B(1)+A-top(1)=6 in flight (steady carry)
  BAR;
  RD_ALOW(0);  // pinned below VM6 by its clobber; consumed by first P1
  RD_B0(0);

#pragma unroll 1
  for (int t = 0; t < NT - 2; t += 2) {
    TILE(0,
         ISSUE(gA1, t + 1, sA1[1]),   // P2-start: A-bot(t+1) -> buf1
         ISSUE(gB0, t + 2, sB0[0]),   // P4-start: B(t+2) -> buf0
         ISSUE(gB1, t + 2, sB1[0]),
         ISSUE(gA0, t + 2, sA0[0]),   // P4-start: A-top(t+2) -> buf0
         VM6);
    TILE(1,
         ISSUE(gA1, t + 2, sA1[0]),
         ISSUE(gB0, t + 3, sB0[1]),
         ISSUE(gB1, t + 3, sB1[1]),
         ISSUE(gA0, t + 3, sA0[1]),
         VM6);
  }
  // tile NT-2 (buf0): stage A-bot(NT-1), full drain at P4, then last tile
  TILE(0, ISSUE(gA1, NT - 1, sA1[1]), NOOP, NOOP, NOOP, VM0);
  TILE_LAST(1);
}

// -------- GEMM1: Q = x Wq^T + bq ; K = x Wk^T + bk  (z selects) --------
// Epilogue: LDS-bounce transpose -> fully coalesced 16B bf16 stores
// (round-5 verified: removes the 2.4x HBM write-amp of scattered 2B stores).
// XCD swizzle (T1): 128 xy-blocks, 8 | 128 -> bijective chunked remap.
__global__ __launch_bounds__(512, 2) void gemm_qk(
    const u16* __restrict__ X, const u16* __restrict__ Wq,
    const u16* __restrict__ Wk, const float* __restrict__ bq,
    const float* __restrict__ bk, u16* __restrict__ Qo, u16* __restrict__ Ko) {
  __shared__ u16 sraw[256 * EPS];  // 132 KiB: mainloop overlay + epilogue tile
  const u16* Bmat = blockIdx.z ? Wk : Wq;
  const float* bias = blockIdx.z ? bk : bq;
  u16* Out = blockIdx.z ? Ko : Qo;
  const int bid = blockIdx.x;
  const int swz = (bid & 7) * 16 + (bid >> 3);  // XCD-chunked, bijective
  const int rowBase = (swz >> 3) * 256;         // by 0..15
  const int colBase = (swz & 7) * 256;          // bx 0..7

  f32x16 acc[4][2] = {};
  mainloop256(X, Bmat, rowBase, colBase, (u16(*)[2][2][8192])sraw, acc);

  const int tid = threadIdx.x;
  const int lane = tid & 63;
  const int wid = tid >> 6;
  const int wmg = wid >> 2;
  const int wng = wid & 3;
  const int l31 = lane & 31;
  const int lhi = lane >> 5;

  float bv[2];
#pragma unroll
  for (int ct = 0; ct < 2; ++ct)
    bv[ct] = bias[colBase + wng * 64 + ct * 32 + l31];

  __syncthreads();  // all waves done with mainloop LDS before overwrite
#pragma unroll
  for (int rt = 0; rt < 4; ++rt) {
#pragma unroll
    for (int ct = 0; ct < 2; ++ct) {
      const int scol = wng * 64 + ct * 32 + l31;
#pragma unroll
      for (int q = 0; q < 4; ++q) {
#pragma unroll
        for (int rr = 0; rr < 4; ++rr) {
          const int srow = wmg * 128 + rt * 32 + 8 * q + rr + 4 * lhi;
          sraw[srow * EPS + scol] = f32_to_bf16(acc[rt][ct][q * 4 + rr] + bv[ct]);
        }
      }
    }
  }
  __syncthreads();  // LDS tile complete
  const int rl = tid >> 5;   // 0..15
  const int c16 = tid & 31;  // which 16B chunk of the row
#pragma unroll
  for (int p = 0; p < 16; ++p) {
    const int row = p * 16 + rl;
    u16x8 v = *(const u16x8*)&sraw[row * EPS + c16 * 8];
    *(u16x8*)&Out[(size_t)(rowBase + row) * DIMK + colBase + c16 * 8] = v;
  }
}

// -------- GEMM2: scores = scale * Q K^T  (bf16 in, fp32 out) --------
// f32 stores: 32 consecutive cols per lane-group = 128B runs, coalesced.
// XCD swizzle (T1): 256 blocks, 8 | 256 -> bijective chunked remap.
__global__ __launch_bounds__(512, 2) void gemm_scores(
    const u16* __restrict__ Qi, const u16* __restrict__ Ki,
    float* __restrict__ out, float scale) {
  __shared__ u16 lds[2][2][2][8192];
  const int bid = blockIdx.x;
  const int swz = (bid & 7) * 32 + (bid >> 3);  // XCD-chunked, bijective
  const int rowBase = (swz >> 4) * 256;         // by 0..15
  const int colBase = (swz & 15) * 256;         // bx 0..15

  f32x16 acc[4][2] = {};
  mainloop256(Qi, Ki, rowBase, colBase, lds, acc);

  const int tid = threadIdx.x;
  const int lane = tid & 63;
  const int wid = tid >> 6;
  const int wmg = wid >> 2;
  const int wng = wid & 3;
  const int l31 = lane & 31;
  const int lhi = lane >> 5;
  const int r0 = rowBase + wmg * 128 + 4 * lhi;
  const int cb = colBase + wng * 64 + l31;
#pragma unroll
  for (int rt = 0; rt < 4; ++rt) {
#pragma unroll
    for (int ct = 0; ct < 2; ++ct) {
      const int col = cb + ct * 32;
#pragma unroll
      for (int q = 0; q < 4; ++q) {
#pragma unroll
        for (int rr = 0; rr < 4; ++rr) {
          const int row = r0 + rt * 32 + 8 * q + rr;
          out[(size_t)row * NSEQ + col] = acc[rt][ct][q * 4 + rr] * scale;
        }
      }
    }
  }
}

extern "C" void kernel_launch(void* const* d_in, const int* in_sizes, int n_in,
                              void* d_out, int out_size, void* d_ws,
                              size_t ws_size, hipStream_t stream) {
  const float* x = (const float*)d_in[0];
  const float* Wq = (const float*)d_in[1];
  const float* bq = (const float*)d_in[2];
  const float* Wk = (const float*)d_in[3];
  const float* bk = (const float*)d_in[4];
  // d_in[5], d_in[6] (W_v, b_v) unused — V never reaches the output.
  float* out = (float*)d_out;

  // workspace layout (64 MB total)
  u16* xb = (u16*)d_ws;                    // 4096x2048 bf16 (16 MB)
  u16* wqb = xb + (size_t)NSEQ * DIMK;     // 2048x2048 bf16 (8 MB)
  u16* wkb = wqb + (size_t)DIMK * DIMK;    // 8 MB
  u16* qb = wkb + (size_t)DIMK * DIMK;     // 16 MB
  u16* kb = qb + (size_t)NSEQ * DIMK;      // 16 MB

  const int total8 = (NSEQ * DIMK + 2 * DIMK * DIMK) / 8;
  cast3_f32_bf16<<<total8 / 256, 256, 0, stream>>>(x, Wq, Wk, xb, wqb, wkb);

  gemm_qk<<<dim3(128, 1, 2), 512, 0, stream>>>(xb, wqb, wkb, bq, bk, qb, kb);

  const float scale = 1.0f / sqrtf((float)DIMK);
  gemm_scores<<<dim3(256, 1, 1), 512, 0, stream>>>(qb, kb, out, scale);
}

// Round 9
// 250.157 us; speedup vs baseline: 1.0532x; 1.0532x over previous
//
#include <hip/hip_runtime.h>
#include <math.h>

#define DIMK 2048
#define NSEQ 4096
#define NT (DIMK / 64)  // 32 K-tiles of BK=64
#define EPS 264          // epilogue LDS row stride (u16) — bank-spread

typedef short bf16x8 __attribute__((ext_vector_type(8)));
typedef float f32x4 __attribute__((ext_vector_type(4)));
typedef unsigned short u16;
typedef unsigned short u16x8 __attribute__((ext_vector_type(8)));

__device__ __forceinline__ u16 f32_to_bf16(float f) {
  unsigned u = __float_as_uint(f);
  u += 0x7fffu + ((u >> 16) & 1u);  // round-to-nearest-even
  return (u16)(u >> 16);
}

__device__ __forceinline__ void async16(const u16* g, u16* l) {
  __builtin_amdgcn_global_load_lds(
      (const __attribute__((address_space(1))) unsigned int*)g,
      (__attribute__((address_space(3))) unsigned int*)l,
      16, 0, 0);
}

// -------- fused fp32 -> bf16 cast for x, Wq, Wk (one launch, 16B stores) ----
__global__ __launch_bounds__(256) void cast3_f32_bf16(
    const float* __restrict__ x, const float* __restrict__ wq,
    const float* __restrict__ wk, u16* __restrict__ xb,
    u16* __restrict__ wqb, u16* __restrict__ wkb) {
  const int xN8 = NSEQ * DIMK / 8;
  const int wN8 = DIMK * DIMK / 8;
  int i = blockIdx.x * 256 + threadIdx.x;
  const float* src;
  u16* dst;
  int j;
  if (i < xN8) { src = x; dst = xb; j = i; }
  else if (i < xN8 + wN8) { src = wq; dst = wqb; j = i - xN8; }
  else { src = wk; dst = wkb; j = i - xN8 - wN8; }
  float4 v0 = ((const float4*)src)[j * 2];
  float4 v1 = ((const float4*)src)[j * 2 + 1];
  u16x8 o;
  o[0] = f32_to_bf16(v0.x); o[1] = f32_to_bf16(v0.y);
  o[2] = f32_to_bf16(v0.z); o[3] = f32_to_bf16(v0.w);
  o[4] = f32_to_bf16(v1.x); o[5] = f32_to_bf16(v1.y);
  o[6] = f32_to_bf16(v1.z); o[7] = f32_to_bf16(v1.w);
  ((u16x8*)dst)[j] = o;
}

// ============ 256x256 woven 3-phase NT GEMM mainloop (round 9) ============
// Round-7 verified base (16x16x32 MFMA, 0 bank conflicts, 43% MfmaUtil),
// two ledger-preserving edits:
//  (1) P2+P3 merged -> 3 barriers/K-tile (the old P2-end barrier ordered
//      no cross-wave hazard once SP1 moved to phase 1).
//  (2) A-bot stage (SP1) moved to phase-1 start: +1 phase of DMA latency
//      margin before its vmcnt retire point; FIFO ledger unchanged.
// Schedule per K-tile:
//   F1: SP1 Abot(t+1)->nxt; {HALF_kk0(a1xb01) | rd b23(cur) | HALF_kk1} BAR1
//   F2: {HALF_kk0(a1xb23) | rd a2(cur) | HALF_kk1;
//        HALF_kk0(a2xb01)   HALF_kk1} BAR2
//   F3: SP3 B(t+2)->cur; SP4 Atop(t+2)->cur; vmcnt(6);
//       {HALF_kk0(a2xb23) | rd a1',b01'(nxt) | HALF_kk1} BAR3
// Hazard ledger (cross-wave stage-vs-read only; within-wave = lgkm):
//  - b01(cur): last read F2 (a2xb01) < BAR2 < B-stage (F3-start).
//  - b23(cur): last read F2 CLa < BAR2 < B-stage.
//  - Atop(cur) region (wmg=0 aLow'/a2 reads): last read woven F2 < BAR2 <
//    Atop-stage (F3-start).
//  - Abot(nxt) region: last consumer = prev-prev tile F3 CLb, separated by
//    >=2 barriers from SP1 at F1-start.
//  - a1'/b01'(nxt) woven in F3 read tile t+1 data: complete via vmcnt(6).
// vmcnt FIFO at F3 (per-thread): outstanding = [B(t+1) 4, Atop(t+1) 2]
// @t-1.F3 + [Abot(t+1) 2]@t.F1 + [B(t+2) 4, Atop(t+2) 2]@t.F3 = 14;
// vmcnt(6) retires the 8 oldest = ALL of tile t+1 before the woven reads
// (pinned below the vmcnt asm by its "memory" clobber). 6 newest carry.

#define VM6 asm volatile("s_waitcnt vmcnt(6)" ::: "memory")
#define VM0 asm volatile("s_waitcnt vmcnt(0)" ::: "memory")
#define BAR __builtin_amdgcn_s_barrier()
#define PRIO1 __builtin_amdgcn_s_setprio(1)
#define PRIO0 __builtin_amdgcn_s_setprio(0)
#define NOOP ((void)0)

#define ISSUE(g, t_, reg)                                     \
  do {                                                        \
    const u16* _gp = (g) + (size_t)(t_) * 64 + stg_goff;      \
    async16(_gp, (reg) + tid * 8);                            \
    async16(_gp + (size_t)64 * DIMK, (reg) + 4096 + tid * 8); \
  } while (0)

// ---- fragment read helpers (fragments live at mainloop scope) ----
#define RD_A1(bi)                                                   \
  _Pragma("unroll") for (int i = 0; i < 4; ++i) {                   \
    a1[i][0] = *(const bf16x8*)&rdA[bi][(i * 16 + fr) * 64 + c0];   \
    a1[i][1] = *(const bf16x8*)&rdA[bi][(i * 16 + fr) * 64 + c1];   \
  }
#define RD_A2(bi)                                                         \
  _Pragma("unroll") for (int i = 0; i < 4; ++i) {                         \
    a2[i][0] = *(const bf16x8*)&rdA[bi][((i + 4) * 16 + fr) * 64 + c0];   \
    a2[i][1] = *(const bf16x8*)&rdA[bi][((i + 4) * 16 + fr) * 64 + c1];   \
  }
#define RD_B01(bi)                                                  \
  _Pragma("unroll") for (int j = 0; j < 2; ++j) {                   \
    b01[j][0] = *(const bf16x8*)&rdB[bi][(j * 16 + fr) * 64 + c0];  \
    b01[j][1] = *(const bf16x8*)&rdB[bi][(j * 16 + fr) * 64 + c1];  \
  }
#define RD_B23(bi)                                                        \
  _Pragma("unroll") for (int j = 0; j < 2; ++j) {                         \
    b23[j][0] = *(const bf16x8*)&rdB[bi][((j + 2) * 16 + fr) * 64 + c0];  \
    b23[j][1] = *(const bf16x8*)&rdB[bi][((j + 2) * 16 + fr) * 64 + c1];  \
  }

// Half-cluster: 8 independent MFMAs (one kk sweep of a C-quadrant).
#define HALF(kk, i0, Aa, j0, Bb)                                         \
  _Pragma("unroll") for (int i = 0; i < 4; ++i)                          \
    _Pragma("unroll") for (int j = 0; j < 2; ++j)                        \
      acc[(i0) + i][(j0) + j] =                                          \
          __builtin_amdgcn_mfma_f32_16x16x32_bf16(                       \
              Aa[i][kk], Bb[j][kk], acc[(i0) + i][(j0) + j], 0, 0, 0);

#define TILE(bi, SP1, SP3A, SP3B, SP4, VMW)  \
  do {                                       \
    /* F1: stage Abot(t+1); a1 x b01, weave b23 reads */ \
    SP1;                                     \
    PRIO1;                                   \
    HALF(0, 0, a1, 0, b01)                   \
    RD_B23(bi);                              \
    HALF(1, 0, a1, 0, b01)                   \
    PRIO0;                                   \
    BAR;                                     \
    /* F2: a1 x b23 (weave a2 reads), then a2 x b01 */ \
    PRIO1;                                   \
    HALF(0, 0, a1, 2, b23)                   \
    RD_A2(bi);                               \
    HALF(1, 0, a1, 2, b23)                   \
    HALF(0, 4, a2, 0, b01)                   \
    HALF(1, 4, a2, 0, b01)                   \
    PRIO0;                                   \
    BAR;                                     \
    /* F3: stages + counted vmcnt; a2 x b23, weave next-buf a1/b01 reads */ \
    SP3A;                                    \
    SP3B;                                    \
    SP4;                                     \
    VMW;                                     \
    PRIO1;                                   \
    HALF(0, 4, a2, 2, b23)                   \
    RD_A1((bi) ^ 1);                         \
    RD_B01((bi) ^ 1);                        \
    HALF(1, 4, a2, 2, b23)                   \
    PRIO0;                                   \
    BAR;                                     \
  } while (0)

// Last K-tile: pure dataflow, no stages, no barriers needed.
#define TILE_LAST(bi)           \
  do {                          \
    PRIO1;                      \
    HALF(0, 0, a1, 0, b01)      \
    RD_B23(bi);                 \
    HALF(1, 0, a1, 0, b01)      \
    HALF(0, 0, a1, 2, b23)      \
    RD_A2(bi);                  \
    HALF(1, 0, a1, 2, b23)      \
    HALF(0, 4, a2, 0, b01)      \
    HALF(1, 4, a2, 0, b01)      \
    HALF(0, 4, a2, 2, b23)      \
    HALF(1, 4, a2, 2, b23)      \
    PRIO0;                      \
  } while (0)

__device__ __forceinline__ void mainloop256(
    const u16* __restrict__ A, const u16* __restrict__ B, int rowBase,
    int colBase, u16 (*lds)[2][2][8192], f32x4 acc[8][4]) {
  const int tid = threadIdx.x;
  const int lane = tid & 63;
  const int wid = tid >> 6;
  const int wmg = wid >> 2;  // 0,1 : which 128-row half of A-tile
  const int wng = wid & 3;   // 0..3: which 64-row strip of B-tile
  const int fr = lane & 15;
  const int kq = lane >> 4;

  // staging: thread covers row (tid>>3), phys chunk (tid&7); pre-swizzled
  // global source chunk = (tid&7) ^ (row&7)  (linear LDS dest, swizzled src).
  const int stg_goff =
      (tid >> 3) * DIMK + (((tid & 7) ^ ((tid >> 3) & 7)) * 8);
  // frag-read phys chunk offsets (elements) for k-step 0 / 1
  const int c0 = (kq ^ (fr & 7)) * 8;
  const int c1 = ((4 + kq) ^ (fr & 7)) * 8;

  const u16* gA0 = A + (size_t)rowBase * DIMK;
  const u16* gA1 = gA0 + (size_t)128 * DIMK;
  const u16* gB0 = B + (size_t)colBase * DIMK;
  const u16* gB1 = gB0 + (size_t)128 * DIMK;

  u16* sA0[2] = {&lds[0][0][0][0], &lds[1][0][0][0]};
  u16* sA1[2] = {&lds[0][0][1][0], &lds[1][0][1][0]};
  u16* sB0[2] = {&lds[0][1][0][0], &lds[1][1][0][0]};
  u16* sB1[2] = {&lds[0][1][1][0], &lds[1][1][1][0]};

  const u16* rdA[2] = {&lds[0][0][wmg][0], &lds[1][0][wmg][0]};
  const u16* rdB[2] = {&lds[0][1][wng >> 1][(wng & 1) * 4096],
                       &lds[1][1][wng >> 1][(wng & 1) * 4096]};

  // fragments live across phases/tiles (read-ahead passes them forward)
  bf16x8 a1[4][2], a2[4][2], b01[2][2], b23[2][2];

  // ---- prologue: tile0 fully (8 ops) + B(1)+A-top(1) (6 ops) ----
  ISSUE(gB0, 0, sB0[0]);
  ISSUE(gB1, 0, sB1[0]);
  ISSUE(gA0, 0, sA0[0]);
  ISSUE(gA1, 0, sA1[0]);
  ISSUE(gB0, 1, sB0[1]);
  ISSUE(gB1, 1, sB1[1]);
  ISSUE(gA0, 1, sA0[1]);
  VM6;  // retire tile0's 8; leave B(1)+A-top(1)=6 in flight (steady carry)
  BAR;
  RD_A1(0);   // pinned below VM6 by its clobber; consumed by first F1
  RD_B01(0);

#pragma unroll 1
  for (int t = 0; t < NT - 2; t += 2) {
    TILE(0,
         ISSUE(gA1, t + 1, sA1[1]),   // F1-start: A-bot(t+1) -> buf1
         ISSUE(gB0, t + 2, sB0[0]),   // F3-start: B(t+2) -> buf0
         ISSUE(gB1, t + 2, sB1[0]),
         ISSUE(gA0, t + 2, sA0[0]),   // F3-start: A-top(t+2) -> buf0
         VM6);
    TILE(1,
         ISSUE(gA1, t + 2, sA1[0]),
         ISSUE(gB0, t + 3, sB0[1]),
         ISSUE(gB1, t + 3, sB1[1]),
         ISSUE(gA0, t + 3, sA0[1]),
         VM6);
  }
  // tile NT-2 (buf0): stage A-bot(NT-1) at F1, full drain at F3, last tile
  TILE(0, ISSUE(gA1, NT - 1, sA1[1]), NOOP, NOOP, NOOP, VM0);
  TILE_LAST(1);
}

// -------- GEMM1: Q = x Wq^T + bq ; K = x Wk^T + bk  (z selects) --------
// Epilogue: LDS-bounce transpose -> fully coalesced 16B bf16 stores
// (round-5 verified: removes the 2.4x HBM write-amp of scattered 2B stores).
__global__ __launch_bounds__(512, 2) void gemm_qk(
    const u16* __restrict__ X, const u16* __restrict__ Wq,
    const u16* __restrict__ Wk, const float* __restrict__ bq,
    const float* __restrict__ bk, u16* __restrict__ Qo, u16* __restrict__ Ko) {
  __shared__ u16 sraw[256 * EPS];  // 132 KiB: mainloop overlay + epilogue tile
  const u16* Bmat = blockIdx.z ? Wk : Wq;
  const float* bias = blockIdx.z ? bk : bq;
  u16* Out = blockIdx.z ? Ko : Qo;
  const int rowBase = blockIdx.y * 256;
  const int colBase = blockIdx.x * 256;

  f32x4 acc[8][4] = {};
  mainloop256(X, Bmat, rowBase, colBase, (u16(*)[2][2][8192])sraw, acc);

  const int tid = threadIdx.x;
  const int lane = tid & 63;
  const int wid = tid >> 6;
  const int wmg = wid >> 2;
  const int wng = wid & 3;
  const int fr = lane & 15;
  const int rq = (lane >> 4) * 4;

  __syncthreads();  // all waves done with mainloop LDS before overwrite
#pragma unroll
  for (int j = 0; j < 4; ++j) {
    const int col = wng * 64 + j * 16 + fr;
    const float bv = bias[colBase + col];
#pragma unroll
    for (int i = 0; i < 8; ++i) {
#pragma unroll
      for (int r = 0; r < 4; ++r) {
        const int row = wmg * 128 + i * 16 + rq + r;
        sraw[row * EPS + col] = f32_to_bf16(acc[i][j][r] + bv);
      }
    }
  }
  __syncthreads();  // LDS tile complete
  const int rl = tid >> 5;   // 0..15
  const int c16 = tid & 31;  // which 16B chunk of the row
#pragma unroll
  for (int p = 0; p < 16; ++p) {
    const int row = p * 16 + rl;
    u16x8 v = *(const u16x8*)&sraw[row * EPS + c16 * 8];
    *(u16x8*)&Out[(size_t)(rowBase + row) * DIMK + colBase + c16 * 8] = v;
  }
}

// -------- GEMM2: scores = scale * Q K^T  (bf16 in, fp32 out) --------
// f32 stores are already full-64B-line per wave-instruction: keep direct.
__global__ __launch_bounds__(512, 2) void gemm_scores(
    const u16* __restrict__ Qi, const u16* __restrict__ Ki,
    float* __restrict__ out, float scale) {
  __shared__ u16 lds[2][2][2][8192];
  const int rowBase = blockIdx.y * 256;
  const int colBase = blockIdx.x * 256;

  f32x4 acc[8][4] = {};
  mainloop256(Qi, Ki, rowBase, colBase, lds, acc);

  const int tid = threadIdx.x;
  const int lane = tid & 63;
  const int wid = tid >> 6;
  const int wmg = wid >> 2;
  const int wng = wid & 3;
  const int fr = lane & 15;
  const int rq = (lane >> 4) * 4;
  const int r0 = rowBase + wmg * 128;
  const int cb = colBase + wng * 64;
#pragma unroll
  for (int j = 0; j < 4; ++j) {
    const int col = cb + j * 16 + fr;
#pragma unroll
    for (int i = 0; i < 8; ++i) {
#pragma unroll
      for (int r = 0; r < 4; ++r) {
        const int row = r0 + i * 16 + rq + r;
        out[(size_t)row * NSEQ + col] = acc[i][j][r] * scale;
      }
    }
  }
}

extern "C" void kernel_launch(void* const* d_in, const int* in_sizes, int n_in,
                              void* d_out, int out_size, void* d_ws,
                              size_t ws_size, hipStream_t stream) {
  const float* x = (const float*)d_in[0];
  const float* Wq = (const float*)d_in[1];
  const float* bq = (const float*)d_in[2];
  const float* Wk = (const float*)d_in[3];
  const float* bk = (const float*)d_in[4];
  // d_in[5], d_in[6] (W_v, b_v) unused — V never reaches the output.
  float* out = (float*)d_out;

  // workspace layout (64 MB total)
  u16* xb = (u16*)d_ws;                    // 4096x2048 bf16 (16 MB)
  u16* wqb = xb + (size_t)NSEQ * DIMK;     // 2048x2048 bf16 (8 MB)
  u16* wkb = wqb + (size_t)DIMK * DIMK;    // 8 MB
  u16* qb = wkb + (size_t)DIMK * DIMK;     // 16 MB
  u16* kb = qb + (size_t)NSEQ * DIMK;      // 16 MB

  const int total8 = (NSEQ * DIMK + 2 * DIMK * DIMK) / 8;
  cast3_f32_bf16<<<total8 / 256, 256, 0, stream>>>(x, Wq, Wk, xb, wqb, wkb);

  gemm_qk<<<dim3(DIMK / 256, NSEQ / 256, 2), 512, 0, stream>>>(xb, wqb, wkb,
                                                               bq, bk, qb, kb);

  const float scale = 1.0f / sqrtf((float)DIMK);
  gemm_scores<<<dim3(NSEQ / 256, NSEQ / 256, 1), 512, 0, stream>>>(qb, kb, out,
                                                                   scale);
}